// Round 7
// baseline (94.846 us; speedup 1.0000x reference)
//
#include <hip/hip_runtime.h>

// BaseHashCode: per-row prefix hash of 64 int digits.
//   prefix_ids[r][t] = ((sum_{i<=t} a[i]*x[r][i] + b) % 1000003) % 65536
//   positions t >= len(r) (len = #nonzero digits) take prefix_ids[(len-1) mod 64].
// Mapping: one row per 16-lane group (== one DPP "row"); each lane owns 4
// consecutive digits via a 16B vector load. All cross-lane traffic via DPP
// (VALU cost, zero DS ops). Streaming loads/stores nontemporal.
// Each WAVE owns a contiguous 8KB tile (8 adjacent 1KB bursts) per outer
// iteration -> long sequential DRAM streams + 8 loads in flight per wave.
// (R6: 4KB tiles gave 93.4us = 5.75 TB/s; R5 showed hand-pipelining hurts.)
// All arithmetic fits int32 (max cumsum < 2^29), matching JAX int32 semantics.

constexpr int PRIME = 1000003;

typedef int vint4 __attribute__((ext_vector_type(4)));

template <int CTRL>
__device__ __forceinline__ int dpp_mov(int v) {
    // old=0, row_mask=0xF, bank_mask=0xF, bound_ctrl=true (invalid lanes -> 0)
    return __builtin_amdgcn_update_dpp(0, v, CTRL, 0xF, 0xF, true);
}

__device__ __forceinline__ vint4 process_chunk(vint4 x, vint4 av, int b, int j) {
    // per-lane products and local inclusive prefix
    int p0 = av.x * x.x;
    int p1 = av.y * x.y;
    int p2 = av.z * x.z;
    int p3 = av.w * x.w;
    int l1 = p0 + p1;
    int l2 = l1 + p2;
    int l3 = l2 + p3;   // lane total

    // 16-lane inclusive scan of lane totals (DPP row_shr, zero-fill)
    int v = l3;
    v += dpp_mov<0x111>(v);   // row_shr:1
    v += dpp_mov<0x112>(v);   // row_shr:2
    v += dpp_mov<0x114>(v);   // row_shr:4
    v += dpp_mov<0x118>(v);   // row_shr:8
    int excl = v - l3;

    int pid0 = ((excl + p0 + b) % PRIME) & 65535;
    int pid1 = ((excl + l1 + b) % PRIME) & 65535;
    int pid2 = ((excl + l2 + b) % PRIME) & 65535;
    int pid3 = ((excl + l3 + b) % PRIME) & 65535;

    // row length = count of nonzero digits; row_ror butterfly -> all lanes
    int cnt = (x.x != 0) + (x.y != 0) + (x.z != 0) + (x.w != 0);
    cnt += dpp_mov<0x128>(cnt);   // row_ror:8
    cnt += dpp_mov<0x124>(cnt);   // row_ror:4
    cnt += dpp_mov<0x122>(cnt);   // row_ror:2
    cnt += dpp_mov<0x121>(cnt);   // row_ror:1

    // broadcast prefix_ids[(cnt-1) mod 64]: zero non-owner, add-reduce
    int g     = (cnt == 0) ? 63 : (cnt - 1);   // JAX: (-1) % 64 == 63
    int slot  = g & 3;                          // row-uniform
    int owner = g >> 2;                         // lane-in-group holding it
    int sel   = (slot == 0) ? pid0 : (slot == 1) ? pid1
              : (slot == 2) ? pid2 : pid3;
    int last  = (j == owner) ? sel : 0;
    last += dpp_mov<0x128>(last);
    last += dpp_mov<0x124>(last);
    last += dpp_mov<0x122>(last);
    last += dpp_mov<0x121>(last);

    int base_pos = j << 2;
    vint4 o;
    o.x = (base_pos + 0 < cnt) ? pid0 : last;
    o.y = (base_pos + 1 < cnt) ? pid1 : last;
    o.z = (base_pos + 2 < cnt) ? pid2 : last;
    o.w = (base_pos + 3 < cnt) ? pid3 : last;
    return o;
}

__global__ __launch_bounds__(256) void BaseHashCode_kernel(
    const vint4* __restrict__ seq4,  // [rows*16] vint4 view of [rows][64] int32
    const int*   __restrict__ a,     // [64]
    const int*   __restrict__ bptr,  // [1]
    vint4* __restrict__ out4,        // [rows*16]
    int total_chunks)                // rows*16 (multiple of 512)
{
    const int lane = threadIdx.x & 63;
    const int j    = lane & 15;          // lane within 16-lane row group
    const int b    = bptr[0];
    const vint4 av = reinterpret_cast<const vint4*>(a)[j];  // a[4j..4j+3]

    const int waves_per_block = blockDim.x >> 6;
    const int gwave       = blockIdx.x * waves_per_block + (threadIdx.x >> 6);
    const int total_waves = gridDim.x * waves_per_block;
    const int outer_step  = total_waves * 512;   // chunks consumed per sweep

    // Each wave owns a contiguous 512-chunk (8KB) tile per outer iteration:
    //   chunk(u) = tb + u*64 + lane,  u = 0..7  (8 adjacent 1KB bursts).
    // tb is wave-uniform (scalar loop) and a multiple of 512, so every
    // 16-lane DPP group maps onto whole rows (offsets all multiples of 16).
    for (int tb = gwave << 9; tb < total_chunks; tb += outer_step) {
        const int c = tb + lane;
        vint4 x0 = __builtin_nontemporal_load(&seq4[c]);
        vint4 x1 = __builtin_nontemporal_load(&seq4[c + 64]);
        vint4 x2 = __builtin_nontemporal_load(&seq4[c + 128]);
        vint4 x3 = __builtin_nontemporal_load(&seq4[c + 192]);
        vint4 x4 = __builtin_nontemporal_load(&seq4[c + 256]);
        vint4 x5 = __builtin_nontemporal_load(&seq4[c + 320]);
        vint4 x6 = __builtin_nontemporal_load(&seq4[c + 384]);
        vint4 x7 = __builtin_nontemporal_load(&seq4[c + 448]);
        vint4 o0 = process_chunk(x0, av, b, j);
        vint4 o1 = process_chunk(x1, av, b, j);
        vint4 o2 = process_chunk(x2, av, b, j);
        vint4 o3 = process_chunk(x3, av, b, j);
        vint4 o4 = process_chunk(x4, av, b, j);
        vint4 o5 = process_chunk(x5, av, b, j);
        vint4 o6 = process_chunk(x6, av, b, j);
        vint4 o7 = process_chunk(x7, av, b, j);
        __builtin_nontemporal_store(o0, &out4[c]);
        __builtin_nontemporal_store(o1, &out4[c + 64]);
        __builtin_nontemporal_store(o2, &out4[c + 128]);
        __builtin_nontemporal_store(o3, &out4[c + 192]);
        __builtin_nontemporal_store(o4, &out4[c + 256]);
        __builtin_nontemporal_store(o5, &out4[c + 320]);
        __builtin_nontemporal_store(o6, &out4[c + 384]);
        __builtin_nontemporal_store(o7, &out4[c + 448]);
    }
}

extern "C" void kernel_launch(void* const* d_in, const int* in_sizes, int n_in,
                              void* d_out, int out_size, void* d_ws, size_t ws_size,
                              hipStream_t stream) {
    const vint4* seq4 = reinterpret_cast<const vint4*>(d_in[0]);
    const int*   a    = reinterpret_cast<const int*>(d_in[1]);
    const int*   bptr = reinterpret_cast<const int*>(d_in[2]);
    vint4*       out4 = reinterpret_cast<vint4*>(d_out);

    const int total_chunks = in_sizes[0] / 4;   // rows*16 vint4 chunks

    const int threads = 256;
    const int blocks  = 2048;   // 8 blocks/CU (max resident); 4 sweeps exactly
    hipLaunchKernelGGL(BaseHashCode_kernel, dim3(blocks), dim3(threads), 0, stream,
                       seq4, a, bptr, out4, total_chunks);
}

// Round 8
// 93.502 us; speedup vs baseline: 1.0144x; 1.0144x over previous
//
#include <hip/hip_runtime.h>

// BaseHashCode: per-row prefix hash of 64 int digits.
//   prefix_ids[r][t] = ((sum_{i<=t} a[i]*x[r][i] + b) % 1000003) % 65536
//   positions t >= len(r) (len = #nonzero digits) take prefix_ids[(len-1) mod 64].
// Mapping: one row per 16-lane group (== one DPP "row"); each lane owns 4
// consecutive digits via a 16B vector load. All cross-lane traffic via DPP
// (VALU cost, zero DS ops). Streaming loads/stores nontemporal.
// Each WAVE owns a contiguous 4KB tile (4 adjacent 1KB bursts) per outer
// iteration -> DRAM row-buffer-local streams. Tile-size scan: strided=101.7us,
// 4KB=93.4us, 8KB=94.8us -> 4KB optimum. Hand-pipelining hurts (R5: -10%).
// All arithmetic fits int32 (max cumsum < 2^29), matching JAX int32 semantics.

constexpr int PRIME = 1000003;

typedef int vint4 __attribute__((ext_vector_type(4)));

template <int CTRL>
__device__ __forceinline__ int dpp_mov(int v) {
    // old=0, row_mask=0xF, bank_mask=0xF, bound_ctrl=true (invalid lanes -> 0)
    return __builtin_amdgcn_update_dpp(0, v, CTRL, 0xF, 0xF, true);
}

__device__ __forceinline__ vint4 process_chunk(vint4 x, vint4 av, int b, int j) {
    // per-lane products and local inclusive prefix
    int p0 = av.x * x.x;
    int p1 = av.y * x.y;
    int p2 = av.z * x.z;
    int p3 = av.w * x.w;
    int l1 = p0 + p1;
    int l2 = l1 + p2;
    int l3 = l2 + p3;   // lane total

    // 16-lane inclusive scan of lane totals (DPP row_shr, zero-fill)
    int v = l3;
    v += dpp_mov<0x111>(v);   // row_shr:1
    v += dpp_mov<0x112>(v);   // row_shr:2
    v += dpp_mov<0x114>(v);   // row_shr:4
    v += dpp_mov<0x118>(v);   // row_shr:8
    int excl = v - l3;

    int pid0 = ((excl + p0 + b) % PRIME) & 65535;
    int pid1 = ((excl + l1 + b) % PRIME) & 65535;
    int pid2 = ((excl + l2 + b) % PRIME) & 65535;
    int pid3 = ((excl + l3 + b) % PRIME) & 65535;

    // row length = count of nonzero digits; row_ror butterfly -> all lanes
    int cnt = (x.x != 0) + (x.y != 0) + (x.z != 0) + (x.w != 0);
    cnt += dpp_mov<0x128>(cnt);   // row_ror:8
    cnt += dpp_mov<0x124>(cnt);   // row_ror:4
    cnt += dpp_mov<0x122>(cnt);   // row_ror:2
    cnt += dpp_mov<0x121>(cnt);   // row_ror:1

    // broadcast prefix_ids[(cnt-1) mod 64]: zero non-owner, add-reduce
    int g     = (cnt == 0) ? 63 : (cnt - 1);   // JAX: (-1) % 64 == 63
    int slot  = g & 3;                          // row-uniform
    int owner = g >> 2;                         // lane-in-group holding it
    int sel   = (slot == 0) ? pid0 : (slot == 1) ? pid1
              : (slot == 2) ? pid2 : pid3;
    int last  = (j == owner) ? sel : 0;
    last += dpp_mov<0x128>(last);
    last += dpp_mov<0x124>(last);
    last += dpp_mov<0x122>(last);
    last += dpp_mov<0x121>(last);

    int base_pos = j << 2;
    vint4 o;
    o.x = (base_pos + 0 < cnt) ? pid0 : last;
    o.y = (base_pos + 1 < cnt) ? pid1 : last;
    o.z = (base_pos + 2 < cnt) ? pid2 : last;
    o.w = (base_pos + 3 < cnt) ? pid3 : last;
    return o;
}

__global__ __launch_bounds__(256) void BaseHashCode_kernel(
    const vint4* __restrict__ seq4,  // [rows*16] vint4 view of [rows][64] int32
    const int*   __restrict__ a,     // [64]
    const int*   __restrict__ bptr,  // [1]
    vint4* __restrict__ out4,        // [rows*16]
    int total_chunks)                // rows*16 (multiple of 256)
{
    const int lane = threadIdx.x & 63;
    const int j    = lane & 15;          // lane within 16-lane row group
    const int b    = bptr[0];
    const vint4 av = reinterpret_cast<const vint4*>(a)[j];  // a[4j..4j+3]

    const int waves_per_block = blockDim.x >> 6;
    const int gwave       = blockIdx.x * waves_per_block + (threadIdx.x >> 6);
    const int total_waves = gridDim.x * waves_per_block;
    const int outer_step  = total_waves * 256;   // chunks consumed per sweep

    // Each wave owns a contiguous 256-chunk (4KB) tile per outer iteration:
    //   chunk(u) = tb + u*64 + lane,  u = 0..3  (4 adjacent 1KB bursts).
    // tb is wave-uniform (scalar loop) and a multiple of 256, so every
    // 16-lane DPP group maps onto whole rows (offsets all multiples of 16).
    for (int tb = gwave << 8; tb < total_chunks; tb += outer_step) {
        const int c = tb + lane;
        vint4 x0 = __builtin_nontemporal_load(&seq4[c]);
        vint4 x1 = __builtin_nontemporal_load(&seq4[c + 64]);
        vint4 x2 = __builtin_nontemporal_load(&seq4[c + 128]);
        vint4 x3 = __builtin_nontemporal_load(&seq4[c + 192]);
        vint4 o0 = process_chunk(x0, av, b, j);
        vint4 o1 = process_chunk(x1, av, b, j);
        vint4 o2 = process_chunk(x2, av, b, j);
        vint4 o3 = process_chunk(x3, av, b, j);
        __builtin_nontemporal_store(o0, &out4[c]);
        __builtin_nontemporal_store(o1, &out4[c + 64]);
        __builtin_nontemporal_store(o2, &out4[c + 128]);
        __builtin_nontemporal_store(o3, &out4[c + 192]);
    }
}

extern "C" void kernel_launch(void* const* d_in, const int* in_sizes, int n_in,
                              void* d_out, int out_size, void* d_ws, size_t ws_size,
                              hipStream_t stream) {
    const vint4* seq4 = reinterpret_cast<const vint4*>(d_in[0]);
    const int*   a    = reinterpret_cast<const int*>(d_in[1]);
    const int*   bptr = reinterpret_cast<const int*>(d_in[2]);
    vint4*       out4 = reinterpret_cast<vint4*>(d_out);

    const int total_chunks = in_sizes[0] / 4;   // rows*16 vint4 chunks

    const int threads = 256;
    const int blocks  = 2048;   // 8 blocks/CU (max resident); 8 sweeps exactly
    hipLaunchKernelGGL(BaseHashCode_kernel, dim3(blocks), dim3(threads), 0, stream,
                       seq4, a, bptr, out4, total_chunks);
}